// Round 9
// baseline (106925.061 us; speedup 1.0000x reference)
//
#include <hip/hip_runtime.h>
#include <stdint.h>

// ================= problem constants =================
#define B_SZ   128
#define T_LEN  2048
#define DIN    256
#define NU     512
#define NOUT   64
#define EPS_F  0.01f
#define GAM_F  0.01f
#define KT     8
#define NTILES (T_LEN / KT)          // 256
#define NPREG  192                   // A k-pairs held in registers (of 256)
#define NPLDS  64                    // A k-pairs held in LDS

typedef uint32_t u32;
typedef _Float16 h16;
typedef _Float16 __attribute__((ext_vector_type(2))) h16x2;
typedef _Float16 __attribute__((ext_vector_type(8))) h16x8;
typedef float    __attribute__((ext_vector_type(4))) f32x4;

// ws layout (u32 units):
//   WS_A   : 131072 (512KB) A = W - W^T - gamma*I, pair-major: [pair p][col j] = pack2(A[2p][j],A[2p+1][j])
//   WS_WH  : 65536  (256KB) Vh_w as MFMA B-frags [(w*8+nt)*8+kkp][lane][4]
//   WS_WZ  : 65536  (256KB) Vz_w same layout
//   WS_PHZ : 128 chains x 8192 (4MB): proj ring [chain][parity][srow 0..7][col 0..511], u32 = (vh,vz) f16
#define WS_A   0
#define WS_WH  131072
#define WS_WZ  196608
#define WS_PHZ 262144

__device__ __forceinline__ u32 pack2(float lo, float hi) {
  h16x2 v; v.x = (h16)lo; v.y = (h16)hi;
  return __builtin_bit_cast(u32, v);
}
__device__ __forceinline__ h16x8 as8(uint4 q) { return __builtin_bit_cast(h16x8, q); }

__device__ __forceinline__ float fdot2(u32 h2, u32 a2, float acc) {
#if __has_builtin(__builtin_amdgcn_fdot2)
  return __builtin_amdgcn_fdot2(__builtin_bit_cast(h16x2, h2),
                                __builtin_bit_cast(h16x2, a2), acc, false);
#else
  h16x2 hh = __builtin_bit_cast(h16x2, h2);
  h16x2 aa = __builtin_bit_cast(h16x2, a2);
  return acc + (float)hh.x * (float)aa.x + (float)hh.y * (float)aa.y;
#endif
}

// ================= prep: pack A (pair-major) + proj weights (MFMA frags) =================
__global__ void antirnn_prep(const float* __restrict__ Vh_w,
                             const float* __restrict__ Vz_w,
                             const float* __restrict__ W,
                             u32* __restrict__ ws) {
  const int idx = blockIdx.x * blockDim.x + threadIdx.x;
  const int stride = gridDim.x * blockDim.x;

  // A pairs: ws[WS_A + p*512 + j] = pack2(A[2p][j], A[2p+1][j])
  for (int u = idx; u < 131072; u += stride) {
    int p = u >> 9, j = u & 511;
    int i0 = 2 * p, i1 = i0 + 1;
    float lo = W[i0 * NU + j] - W[j * NU + i0] - (i0 == j ? GAM_F : 0.f);
    float hi = W[i1 * NU + j] - W[j * NU + i1] - (i1 == j ? GAM_F : 0.f);
    ws[WS_A + u] = pack2(lo, hi);
  }
  // W-frags: U2 = (((w*8+nt)*8+kkp)*64+l)*4+e ; unit n = w*128+nt*16+(l&15), k over DIN
  for (int u = idx; u < 65536; u += stride) {
    int e   = u & 3;
    int l   = (u >> 2) & 63;
    int kkp = (u >> 8) & 7;
    int nt  = (u >> 11) & 7;
    int w   = (u >> 14) & 3;
    int n   = w * 128 + nt * 16 + (l & 15);
    int k0  = kkp * 32 + (l >> 4) * 8 + 2 * e;
    ws[WS_WH + u] = pack2(Vh_w[n * DIN + k0], Vh_w[n * DIN + k0 + 1]);
    ws[WS_WZ + u] = pack2(Vz_w[n * DIN + k0], Vz_w[n * DIN + k0 + 1]);
  }
}

// ================= scan: 128 WGs x 256 thr (4 waves, 1 wave/SIMD); one WG = one chain =================
__global__ __launch_bounds__(256, 1) void antirnn_scan(
    const float* __restrict__ x,
    const float* __restrict__ vh_b, const float* __restrict__ vz_b,
    const float* __restrict__ fc_w, const float* __restrict__ fc_b,
    u32* __restrict__ ws, float* __restrict__ out) {

  __shared__ u32 ldsA[NPLDS * NU];   // 128KB: A pairs 192..255, [pp][col]
  __shared__ u32 hp[2][256];         // 2KB: h as f16x2 pairs, dbuf by step parity
  __shared__ u32 xs[1024];           // 4KB: x tile f16 [row 0..7][256 vals], row-xor-swizzled

  const int tid = threadIdx.x;
  const int w   = tid >> 6;          // wave: proj cols [w*128, w*128+128)
  const int l   = tid & 63;
  const int lg  = l >> 4;
  const int ln  = l & 15;
  const int b   = blockIdx.x;
  const int j0  = 2 * tid, j1 = j0 + 1;   // dot-owned columns

  // ---- A registers: pairs 0..191 for cols j0,j1 (coalesced b64 loads) ----
  u32 a0[NPREG], a1[NPREG];
  {
    const u32* Ab = ws + WS_A + j0;
#pragma unroll
    for (int p = 0; p < NPREG; ++p) {
      uint2 q = *reinterpret_cast<const uint2*>(Ab + p * NU);
      a0[p] = q.x; a1[p] = q.y;
    }
  }
  // ---- LDS A: pairs 192..255 ----
#pragma unroll 1
  for (int i = 0; i < 32; ++i) {
    int f = i * 1024 + tid * 4;
    uint4 v = *reinterpret_cast<const uint4*>(ws + WS_A + NPREG * NU + f);
    *reinterpret_cast<uint4*>(&ldsA[f]) = v;
  }

  hp[0][tid] = 0; hp[1][tid] = 0;
  const float bh0 = vh_b[j0], bz0 = vz_b[j0];
  const float bh1 = vh_b[j1], bz1 = vz_b[j1];
  float hv0 = 0.f, hv1 = 0.f;

  const uint4* WH4 = reinterpret_cast<const uint4*>(ws + WS_WH);
  const uint4* WZ4 = reinterpret_cast<const uint4*>(ws + WS_WZ);
  const float* xb  = x + (long)b * T_LEN * DIN;
  u32* wphz = ws + WS_PHZ + b * 8192;

  __syncthreads();

  // ---- prologue: proj tile 0 -> parity 0 (direct global x reads) ----
#pragma unroll 1
  for (int pb = 0; pb < 4; ++pb) {
    const int ntA = 2 * pb, ntB = ntA + 1;
    const uint4* bHA = WH4 + ((w * 8 + ntA) * 8) * 64 + l;
    const uint4* bHB = WH4 + ((w * 8 + ntB) * 8) * 64 + l;
    const uint4* bZA = WZ4 + ((w * 8 + ntA) * 8) * 64 + l;
    const uint4* bZB = WZ4 + ((w * 8 + ntB) * 8) * 64 + l;
    const float* xrow = xb + (long)(ln & 7) * DIN;
    f32x4 pA = {0.f,0.f,0.f,0.f}, pB = pA, qA = pA, qB = pA;
#pragma unroll 1
    for (int kkp = 0; kkp < 8; ++kkp) {
      float4 xv0 = *reinterpret_cast<const float4*>(xrow + kkp * 32 + lg * 8);
      float4 xv1 = *reinterpret_cast<const float4*>(xrow + kkp * 32 + lg * 8 + 4);
      h16x8 xf;
      xf[0]=(h16)xv0.x; xf[1]=(h16)xv0.y; xf[2]=(h16)xv0.z; xf[3]=(h16)xv0.w;
      xf[4]=(h16)xv1.x; xf[5]=(h16)xv1.y; xf[6]=(h16)xv1.z; xf[7]=(h16)xv1.w;
      pA = __builtin_amdgcn_mfma_f32_16x16x32_f16(xf, as8(bHA[kkp*64]), pA, 0,0,0);
      pB = __builtin_amdgcn_mfma_f32_16x16x32_f16(xf, as8(bHB[kkp*64]), pB, 0,0,0);
      qA = __builtin_amdgcn_mfma_f32_16x16x32_f16(xf, as8(bZA[kkp*64]), qA, 0,0,0);
      qB = __builtin_amdgcn_mfma_f32_16x16x32_f16(xf, as8(bZB[kkp*64]), qB, 0,0,0);
    }
    if (lg < 2) {
#pragma unroll
      for (int r = 0; r < 4; ++r) {
        int srow = 4 * lg + r;
        wphz[srow * 512 + (w * 128 + ntA * 16 + ln)] = pack2(pA[r], qA[r]);
        wphz[srow * 512 + (w * 128 + ntB * 16 + ln)] = pack2(pB[r], qB[r]);
      }
    }
  }
  __syncthreads();

  // ---- main loop: 256 tiles x 8 steps ----
#pragma unroll 1
  for (int tile = 0; tile < NTILES; ++tile) {
    // stage x[tile+1] tile into xs (f16, row-xor-swizzled)
    {
      const int tsrc = (tile + 1 < NTILES) ? (tile + 1) : (NTILES - 1);
      const float* xr = xb + (long)(tsrc * KT) * DIN;
      const int r  = tid >> 5;
      const int c8 = (tid & 31) * 8;
      float4 v0 = *reinterpret_cast<const float4*>(xr + r * DIN + c8);
      float4 v1 = *reinterpret_cast<const float4*>(xr + r * DIN + c8 + 4);
      uint4 pk;
      pk.x = pack2(v0.x, v0.y); pk.y = pack2(v0.z, v0.w);
      pk.z = pack2(v1.x, v1.y); pk.w = pack2(v1.z, v1.w);
      char* dst = reinterpret_cast<char*>(xs) + ((r * 512 + c8 * 2) ^ (r << 4));
      *reinterpret_cast<uint4*>(dst) = pk;
    }
    __syncthreads();

    const int consBase = (tile & 1) * 4096;
    const int prodBase = ((tile + 1) & 1) * 4096;
    f32x4 pA = {0.f,0.f,0.f,0.f}, pB = pA, qA = pA, qB = pA;

#pragma unroll 1
    for (int sp = 0; sp < KT; ++sp) {
      const int pb  = sp >> 1;
      const int phs = sp & 1;
      const int ntA = 2 * pb, ntB = ntA + 1;

      // --- consume vh/vz for this step (volatile L2 reads; land during dot) ---
      u32 pv0 = *(const volatile u32*)(wphz + consBase + sp * 512 + j0);
      u32 pv1 = *(const volatile u32*)(wphz + consBase + sp * 512 + j1);

      // --- recurrence dot: u_j = sum_p fdot2(h_pair, A_pair_j); lane-local cols ---
      const u32* hpc = hp[phs];
      float u0 = 0.f, u1 = 0.f;
#pragma unroll
      for (int pbk = 0; pbk < NPREG / 4; ++pbk) {
        uint4 hq = *reinterpret_cast<const uint4*>(&hpc[pbk * 4]);
        const u32* hqe = reinterpret_cast<const u32*>(&hq);
#pragma unroll
        for (int e = 0; e < 4; ++e) {
          u0 = fdot2(hqe[e], a0[pbk * 4 + e], u0);
          u1 = fdot2(hqe[e], a1[pbk * 4 + e], u1);
        }
      }
#pragma unroll
      for (int pbk = 0; pbk < NPLDS / 4; ++pbk) {
        uint4 hq = *reinterpret_cast<const uint4*>(&hpc[NPREG + pbk * 4]);
        const u32* hqe = reinterpret_cast<const u32*>(&hq);
#pragma unroll
        for (int e = 0; e < 4; ++e) {
          uint2 av = *reinterpret_cast<const uint2*>(&ldsA[(pbk * 4 + e) * NU + j0]);
          u0 = fdot2(hqe[e], av.x, u0);
          u1 = fdot2(hqe[e], av.y, u1);
        }
      }

      // --- proj quarter for tile+1 (4 kkp x 4 MFMA) from xs ---
      {
        const uint4* bHA = WH4 + ((w * 8 + ntA) * 8) * 64 + l;
        const uint4* bHB = WH4 + ((w * 8 + ntB) * 8) * 64 + l;
        const uint4* bZA = WZ4 + ((w * 8 + ntA) * 8) * 64 + l;
        const uint4* bZB = WZ4 + ((w * 8 + ntB) * 8) * 64 + l;
        if (phs == 0) { pA = (f32x4){0.f,0.f,0.f,0.f}; pB = pA; qA = pA; qB = pA; }
        const int r = ln & 7;
#pragma unroll
        for (int kq = 0; kq < 4; ++kq) {
          const int kkp = phs * 4 + kq;
          const char* src = reinterpret_cast<const char*>(xs) +
                            ((r * 512 + kkp * 64 + lg * 16) ^ (r << 4));
          h16x8 xf = *reinterpret_cast<const h16x8*>(src);
          pA = __builtin_amdgcn_mfma_f32_16x16x32_f16(xf, as8(bHA[kkp*64]), pA, 0,0,0);
          pB = __builtin_amdgcn_mfma_f32_16x16x32_f16(xf, as8(bHB[kkp*64]), pB, 0,0,0);
          qA = __builtin_amdgcn_mfma_f32_16x16x32_f16(xf, as8(bZA[kkp*64]), qA, 0,0,0);
          qB = __builtin_amdgcn_mfma_f32_16x16x32_f16(xf, as8(bZB[kkp*64]), qB, 0,0,0);
        }
        if (phs == 1 && lg < 2) {
#pragma unroll
          for (int r2 = 0; r2 < 4; ++r2) {
            int srow = 4 * lg + r2;
            wphz[prodBase + srow * 512 + (w * 128 + ntA * 16 + ln)] = pack2(pA[r2], qA[r2]);
            wphz[prodBase + srow * 512 + (w * 128 + ntB * 16 + ln)] = pack2(pB[r2], qB[r2]);
          }
        }
      }

      // --- epilogue: both owned cols fully lane-local; no shuffles ---
      {
        h16x2 q0 = __builtin_bit_cast(h16x2, pv0);
        h16x2 q1 = __builtin_bit_cast(h16x2, pv1);
        float uh0 = u0 + (float)q0.x + bh0, uz0 = u0 + (float)q0.y + bz0;
        float uh1 = u1 + (float)q1.x + bh1, uz1 = u1 + (float)q1.y + bz1;
        float c0h = fminf(fmaxf(uh0, -20.f), 20.f);
        float c1h = fminf(fmaxf(uh1, -20.f), 20.f);
        float e0 = __expf(2.f * c0h), e1 = __expf(2.f * c1h);
        float th0 = 1.f - 2.f / (e0 + 1.f), th1 = 1.f - 2.f / (e1 + 1.f);
        float sg0 = 1.f / (1.f + __expf(-uz0)), sg1 = 1.f / (1.f + __expf(-uz1));
        hv0 += EPS_F * th0 * sg0;
        hv1 += EPS_F * th1 * sg1;
        hp[1 - phs][tid] = pack2(hv0, hv1);
      }
      __syncthreads();
    }
  }

  // ---- final fc: out[b][o] = fc_b[o] + sum_c h[c]*fc_w[o][c] (reuse xs as f32 h buffer) ----
  float* hbuf = reinterpret_cast<float*>(xs);
  hbuf[j0] = hv0;
  hbuf[j1] = hv1;
  __syncthreads();
  if (tid < NOUT) {
    float acc = fc_b[tid];
    const float* fr = fc_w + tid * NU;
#pragma unroll 4
    for (int c = 0; c < NU; ++c) acc += hbuf[c] * fr[c];
    out[b * NOUT + tid] = acc;
  }
}

// ================= launcher =================
extern "C" void kernel_launch(void* const* d_in, const int* in_sizes, int n_in,
                              void* d_out, int out_size, void* d_ws, size_t ws_size,
                              hipStream_t stream) {
  const float* x    = (const float*)d_in[0];
  const float* Vh_w = (const float*)d_in[1];
  const float* Vh_b = (const float*)d_in[2];
  const float* Vz_w = (const float*)d_in[3];
  const float* Vz_b = (const float*)d_in[4];
  const float* W    = (const float*)d_in[5];
  const float* fc_w = (const float*)d_in[6];
  const float* fc_b = (const float*)d_in[7];
  float* out = (float*)d_out;
  u32*   ws  = (u32*)d_ws;

  antirnn_prep<<<512, 256, 0, stream>>>(Vh_w, Vz_w, W, ws);
  antirnn_scan<<<128, 256, 0, stream>>>(x, Vh_b, Vz_b, fc_w, fc_b, ws, out);
}